// Round 8
// baseline (173.859 us; speedup 1.0000x reference)
//
#include <hip/hip_runtime.h>
#include <hip/hip_bf16.h>

#define NN 100000
#define CC 128
#define KK 32
#define BB 64
#define CH 4                // chunks (of 32 nodes) per fused block
#define NCHUNK (NN / 32)    // 3125
#define NSLOT 16            // partial-tile slots per graph (graph <= 14 blocks)

typedef __bf16 bf16x8 __attribute__((ext_vector_type(8)));
typedef float  f32x4  __attribute__((ext_vector_type(4)));

__device__ __forceinline__ unsigned short f2bf(float v) {
    union { __bf16 h; unsigned short s; } u;
    u.h = (__bf16)v;                     // native RNE cvt on gfx950
    return u.s;
}
__device__ __forceinline__ float bf2f(unsigned short h) {
    union { unsigned u; float f; } a; a.u = ((unsigned)h) << 16;
    return a.f;
}
// unpack 8 uints (hi|lo<<16) -> two bf16x8 via v_perm_b32
__device__ __forceinline__ void unpack_hilo(uint4 a, uint4 b,
                                            bf16x8& hi8, bf16x8& lo8) {
    union { unsigned u[4]; bf16x8 v; } H, L;
    H.u[0] = __builtin_amdgcn_perm(a.y, a.x, 0x05040100u);
    H.u[1] = __builtin_amdgcn_perm(a.w, a.z, 0x05040100u);
    H.u[2] = __builtin_amdgcn_perm(b.y, b.x, 0x05040100u);
    H.u[3] = __builtin_amdgcn_perm(b.w, b.z, 0x05040100u);
    L.u[0] = __builtin_amdgcn_perm(a.y, a.x, 0x07060302u);
    L.u[1] = __builtin_amdgcn_perm(a.w, a.z, 0x07060302u);
    L.u[2] = __builtin_amdgcn_perm(b.y, b.x, 0x07060302u);
    L.u[3] = __builtin_amdgcn_perm(b.w, b.z, 0x07060302u);
    hi8 = H.v; lo8 = L.v;
}

// ---------------------------------------------------------------------------
// Kernel 1 (prep): bounds + W1 & W2 -> bf16 hi/lo MFMA B-fragments + zero the
// partial-tile buffer. Grid: 256 blocks x 256 = 65536 threads.
// ---------------------------------------------------------------------------
__global__ __launch_bounds__(256) void hp_prep(const int* __restrict__ batch,
                                               const float* __restrict__ W1,
                                               const float* __restrict__ W2,
                                               int* __restrict__ bounds,
                                               unsigned short* __restrict__ w1f,
                                               unsigned short* __restrict__ w2f,
                                               float* __restrict__ part) {
    if (blockIdx.x == 0 && threadIdx.x <= BB) {
        const int b = threadIdx.x;
        int lo = 0, hi = NN;
        while (lo < hi) {
            const int mid = (lo + hi) >> 1;
            if (batch[mid] < b) lo = mid + 1; else hi = mid;
        }
        bounds[b] = lo;
    }
    const int t = blockIdx.x * 256 + threadIdx.x;
    if (t < 16384) {   // W1 fragments
        const int idx  = t;
        const int j    = idx & 7;
        const int lane = (idx >> 3) & 63;
        const int nt   = (idx >> 9) & 7;
        const int kt   = idx >> 12;
        const int k = kt * 32 + (lane >> 4) * 8 + j;
        const int n = nt * 16 + (lane & 15);
        const float w = W1[k * CC + n];
        const unsigned short h = f2bf(w);
        w1f[idx]         = h;
        w1f[16384 + idx] = f2bf(w - bf2f(h));
    }
    if (t < 4096) {    // W2 fragments
        const int idx  = t;
        const int j    = idx & 7;
        const int lane = (idx >> 3) & 63;
        const int nt   = (idx >> 9) & 1;
        const int kt   = idx >> 10;
        const int k = kt * 32 + (lane >> 4) * 8 + j;
        const int n = nt * 16 + (lane & 15);
        const float w = W2[k * KK + n];
        const unsigned short h = f2bf(w);
        w2f[idx]        = h;
        w2f[4096 + idx] = f2bf(w - bf2f(h));
    }
    // zero the partial-tile buffer [B][NSLOT][K][C] (fused writes sparse slots)
    const float4 z = make_float4(0.f, 0.f, 0.f, 0.f);
    for (int i = t; i < BB * NSLOT * KK * CC / 4; i += 65536)
        *(float4*)(part + (size_t)i * 4) = z;
}

// ---------------------------------------------------------------------------
// Kernel 2 (fused): per block, CH consecutive 32-node chunks.
// 4 barriers per chunk:
//   stage (cvt PREFETCHED regs -> xa, xbL[ch&1]; issue ch+1 prefetch) -> B1 ->
//   layer1 MFMA -> B2 -> pack hs16 -> B3 ->
//   { waves 0,1: layer2 both n-halves + in-wave softmax -> lgT } -> B4 ->
//   s_out float4 store + pool MFMA + flush (plain stores to part[g][slot]).
// T14 async-stage: all x inputs for chunk ch+1 are register-loaded during
// chunk ch's stage phase (in flight across barriers; HBM latency hidden under
// a full chunk of compute). xbL double-buffered to drop the top barrier.
// ---------------------------------------------------------------------------
__global__ __launch_bounds__(256, 3) void hp_fused(
    const float* __restrict__ x,
    const unsigned short* __restrict__ w1f,
    const unsigned short* __restrict__ w2f,
    const float* __restrict__ b1,
    const float* __restrict__ b2,
    const int* __restrict__ batch,
    const int* __restrict__ bounds,
    float* __restrict__ s_out,
    float* __restrict__ part)
{
    __shared__ __align__(16) char uni[16896];                  // xa / hs16 overlay
    __shared__ __align__(16) unsigned short xbL[2][8 * 64 * 8]; // 16 KB dbuf B-frags
    __shared__ float lgT[32][36];                              // [node][k] s values

    unsigned short* xa   = (unsigned short*)uni;   // [split][q=mt*4+kt][lane][8]
    unsigned int*   hs16 = (unsigned int*)uni;     // [node][132]: hi | lo<<16

    const int t    = threadIdx.x;
    const int wave = __builtin_amdgcn_readfirstlane(t >> 6);
    const int lane = t & 63;

    const int pmt   = wave & 1;                    // pool: k-half
    const int chalf = wave >> 1;                   // pool: c-half
    const int nrow  = (lane >> 4) * 8;             // pool: first node row of lane

    // hoisted loop-invariant biases
    const float bv_epi0 = b1[(2 * wave + 0) * 16 + (lane & 15)];
    const float bv_epi1 = b1[(2 * wave + 1) * 16 + (lane & 15)];
    const float b2lo = b2[lane & 15];
    const float b2hi = b2[16 + (lane & 15)];

    f32x4 pacc[4];
    #pragma unroll
    for (int i = 0; i < 4; ++i) pacc[i] = (f32x4){0.f, 0.f, 0.f, 0.f};

    int cg = __builtin_amdgcn_readfirstlane(batch[blockIdx.x * (CH * 32)]);

    // flush current accumulator into part[g][slot] (plain stores, no atomics)
    auto flush = [&](int g) {
        const int slot = blockIdx.x - (bounds[g] >> 7);   // 128 nodes per block
        float* op = part + ((size_t)g * NSLOT + slot) * (KK * CC);
        #pragma unroll
        for (int i = 0; i < 4; ++i) {
            const int c = (chalf * 4 + i) * 16 + (lane & 15);
            #pragma unroll
            for (int r = 0; r < 4; ++r) {
                const int k = pmt * 16 + (lane >> 4) * 4 + r;
                op[k * CC + c] = pacc[i][r];
            }
            pacc[i] = (f32x4){0.f, 0.f, 0.f, 0.f};
        }
    };

    // ---- prologue prefetch for chunk 0 of this block (T14) ----
    float4 pva0, pvb0, pva1, pvb1;   // A-frag inputs: 2 node-halves x 8 floats
    float  pxb0[8], pxb1[8];         // xbL inputs: 2 c-columns x 8 node rows
    {
        const int base0 = blockIdx.x * (CH * 32);
        const int n0 = base0 + (lane & 15);
        const int n1 = base0 + 16 + (lane & 15);
        const int ck = wave * 32 + (lane >> 4) * 8;
        pva0 = *(const float4*)(x + (size_t)n0 * CC + ck);
        pvb0 = *(const float4*)(x + (size_t)n0 * CC + ck + 4);
        pva1 = *(const float4*)(x + (size_t)n1 * CC + ck);
        pvb1 = *(const float4*)(x + (size_t)n1 * CC + ck + 4);
        const int c0 = (wave * 2 + 0) * 16 + (lane & 15);
        const int c1 = (wave * 2 + 1) * 16 + (lane & 15);
        const int nr = base0 + nrow;
        #pragma unroll
        for (int j = 0; j < 8; ++j) {
            pxb0[j] = x[(size_t)(nr + j) * CC + c0];
            pxb1[j] = x[(size_t)(nr + j) * CC + c1];
        }
    }

    #pragma unroll 1
    for (int ch = 0; ch < CH; ++ch) {
        const int chunk = blockIdx.x * CH + ch;
        if (chunk >= NCHUNK) break;
        const int base = chunk * 32;

        // ---- stage: cvt prefetched regs -> xa hi/lo A-frags ----
        {
            const float v0[8] = {pva0.x, pva0.y, pva0.z, pva0.w,
                                 pvb0.x, pvb0.y, pvb0.z, pvb0.w};
            const float v1[8] = {pva1.x, pva1.y, pva1.z, pva1.w,
                                 pvb1.x, pvb1.y, pvb1.z, pvb1.w};
            union { unsigned short s[8]; uint4 u; } H0, L0, H1, L1;
            #pragma unroll
            for (int j = 0; j < 8; ++j) {
                H0.s[j] = f2bf(v0[j]); L0.s[j] = f2bf(v0[j] - bf2f(H0.s[j]));
                H1.s[j] = f2bf(v1[j]); L1.s[j] = f2bf(v1[j] - bf2f(H1.s[j]));
            }
            unsigned short* d0 = xa + ((0 * 4 + wave) * 64 + lane) * 8;
            unsigned short* d1 = xa + ((1 * 4 + wave) * 64 + lane) * 8;
            *(uint4*)(d0)        = H0.u;
            *(uint4*)(d0 + 4096) = L0.u;
            *(uint4*)(d1)        = H1.u;
            *(uint4*)(d1 + 4096) = L1.u;
        }

        // ---- emit pool B-frags into xbL[ch&1] from prefetched regs ----
        {
            union { unsigned short s[8]; uint4 u; } Hb0, Hb1;
            #pragma unroll
            for (int j = 0; j < 8; ++j) {
                Hb0.s[j] = f2bf(pxb0[j]);
                Hb1.s[j] = f2bf(pxb1[j]);
            }
            *(uint4*)(&xbL[ch & 1][((wave * 2 + 0) * 64 + lane) * 8]) = Hb0.u;
            *(uint4*)(&xbL[ch & 1][((wave * 2 + 1) * 64 + lane) * 8]) = Hb1.u;
        }

        // ---- issue chunk ch+1 prefetch (regs stay in flight across barriers) ----
        if (ch + 1 < CH && chunk + 1 < NCHUNK) {
            const int nb = base + 32;
            const int n0 = nb + (lane & 15);
            const int n1 = nb + 16 + (lane & 15);
            const int ck = wave * 32 + (lane >> 4) * 8;
            pva0 = *(const float4*)(x + (size_t)n0 * CC + ck);
            pvb0 = *(const float4*)(x + (size_t)n0 * CC + ck + 4);
            pva1 = *(const float4*)(x + (size_t)n1 * CC + ck);
            pvb1 = *(const float4*)(x + (size_t)n1 * CC + ck + 4);
            const int c0 = (wave * 2 + 0) * 16 + (lane & 15);
            const int c1 = (wave * 2 + 1) * 16 + (lane & 15);
            const int nr = nb + nrow;
            #pragma unroll
            for (int j = 0; j < 8; ++j) {
                pxb0[j] = x[(size_t)(nr + j) * CC + c0];
                pxb1[j] = x[(size_t)(nr + j) * CC + c1];
            }
        }
        __syncthreads();                                         // B1

        // ---- layer-1 MFMA; wave owns n-tiles 2w, 2w+1 ----
        f32x4 acc[2][2];
        #pragma unroll
        for (int mt = 0; mt < 2; ++mt)
            #pragma unroll
            for (int nl = 0; nl < 2; ++nl)
                acc[mt][nl] = (f32x4){0.f, 0.f, 0.f, 0.f};

        #pragma unroll
        for (int kt = 0; kt < 4; ++kt) {
            bf16x8 ah[2], al[2];
            #pragma unroll
            for (int mt = 0; mt < 2; ++mt) {
                ah[mt] = *(const bf16x8*)(xa + ((mt * 4 + kt) * 64 + lane) * 8);
                al[mt] = *(const bf16x8*)(xa + 4096 + ((mt * 4 + kt) * 64 + lane) * 8);
            }
            #pragma unroll
            for (int nl = 0; nl < 2; ++nl) {
                const int nt = 2 * wave + nl;
                const bf16x8 wh = *(const bf16x8*)(w1f + ((kt * 8 + nt) * 64 + lane) * 8);
                const bf16x8 wl = *(const bf16x8*)(w1f + 16384 + ((kt * 8 + nt) * 64 + lane) * 8);
                #pragma unroll
                for (int mt = 0; mt < 2; ++mt) {
                    acc[mt][nl] = __builtin_amdgcn_mfma_f32_16x16x32_bf16(ah[mt], wh, acc[mt][nl], 0, 0, 0);
                    acc[mt][nl] = __builtin_amdgcn_mfma_f32_16x16x32_bf16(al[mt], wh, acc[mt][nl], 0, 0, 0);
                    acc[mt][nl] = __builtin_amdgcn_mfma_f32_16x16x32_bf16(ah[mt], wl, acc[mt][nl], 0, 0, 0);
                }
            }
        }
        __syncthreads();                                         // B2 (xa dead)

        // ---- epilogue: bias+relu, pack hi|lo<<16 -> hs16[node][132] ----
        #pragma unroll
        for (int nl = 0; nl < 2; ++nl) {
            const float bv = nl ? bv_epi1 : bv_epi0;
            const int c = (2 * wave + nl) * 16 + (lane & 15);
            #pragma unroll
            for (int mt = 0; mt < 2; ++mt)
                #pragma unroll
                for (int r = 0; r < 4; ++r) {
                    const int node = mt * 16 + (lane >> 4) * 4 + r;
                    const float h = fmaxf(acc[mt][nl][r] + bv, 0.f);
                    const unsigned short hi = f2bf(h);
                    const unsigned short lo = f2bf(h - bf2f(hi));
                    hs16[node * 132 + c] = (unsigned)hi | ((unsigned)lo << 16);
                }
        }
        __syncthreads();                                         // B3

        // ---- phase 2: waves 0,1 do layer2 (both n-halves) + in-wave softmax ----
        if (wave < 2) {
            const int mt2 = wave;
            f32x4 dacc[2];
            dacc[0] = (f32x4){0.f, 0.f, 0.f, 0.f};
            dacc[1] = (f32x4){0.f, 0.f, 0.f, 0.f};
            #pragma unroll
            for (int kt = 0; kt < 4; ++kt) {
                const unsigned* hp = hs16 + (mt2 * 16 + (lane & 15)) * 132
                                          + kt * 32 + (lane >> 4) * 8;
                const uint4 u0 = *(const uint4*)hp;
                const uint4 u1 = *(const uint4*)(hp + 4);
                bf16x8 ah, al;
                unpack_hilo(u0, u1, ah, al);
                #pragma unroll
                for (int nt2 = 0; nt2 < 2; ++nt2) {
                    const bf16x8 wh = *(const bf16x8*)(w2f + ((kt * 2 + nt2) * 64 + lane) * 8);
                    const bf16x8 wl = *(const bf16x8*)(w2f + 4096 + ((kt * 2 + nt2) * 64 + lane) * 8);
                    dacc[nt2] = __builtin_amdgcn_mfma_f32_16x16x32_bf16(ah, wh, dacc[nt2], 0, 0, 0);
                    dacc[nt2] = __builtin_amdgcn_mfma_f32_16x16x32_bf16(al, wh, dacc[nt2], 0, 0, 0);
                    dacc[nt2] = __builtin_amdgcn_mfma_f32_16x16x32_bf16(ah, wl, dacc[nt2], 0, 0, 0);
                }
            }
            // in-wave softmax: lane holds k = lane&15 (+0/+16); node = (lane>>4)*4+r
            float lg0[4], lg1[4], m[4];
            #pragma unroll
            for (int r = 0; r < 4; ++r) {
                lg0[r] = dacc[0][r] + b2lo;
                lg1[r] = dacc[1][r] + b2hi;
                m[r] = fmaxf(lg0[r], lg1[r]);
            }
            #pragma unroll
            for (int msk = 1; msk < 16; msk <<= 1)
                #pragma unroll
                for (int r = 0; r < 4; ++r)
                    m[r] = fmaxf(m[r], __shfl_xor(m[r], msk));
            float e0[4], e1[4], sm[4];
            #pragma unroll
            for (int r = 0; r < 4; ++r) {
                e0[r] = __expf(lg0[r] - m[r]);
                e1[r] = __expf(lg1[r] - m[r]);
                sm[r] = e0[r] + e1[r];
            }
            #pragma unroll
            for (int msk = 1; msk < 16; msk <<= 1)
                #pragma unroll
                for (int r = 0; r < 4; ++r)
                    sm[r] += __shfl_xor(sm[r], msk);
            #pragma unroll
            for (int r = 0; r < 4; ++r) {
                const float inv = 1.f / sm[r];
                const int node = mt2 * 16 + (lane >> 4) * 4 + r;
                lgT[node][lane & 15]        = e0[r] * inv;
                lgT[node][16 + (lane & 15)] = e1[r] * inv;
            }
        }
        __syncthreads();                                         // B4

        // ---- s_out float4 store from lgT ----
        {
            const int node = lane & 31;
            const int koff = ((lane >> 5) << 4) + wave * 4;
            const float4 s4 = *(const float4*)&lgT[node][koff];
            *(float4*)(s_out + (size_t)(base + node) * KK + koff) = s4;
        }

        // ---- pool: s^T x accumulate (per-wave quadrant, no barriers) ----
        {
            union { unsigned short s[8]; bf16x8 v; } A;
            const int kA = pmt * 16 + (lane & 15);
            #pragma unroll
            for (int j = 0; j < 8; ++j)
                A.s[j] = f2bf(lgT[nrow + j][kA]);
            bf16x8 Bv[4];
            #pragma unroll
            for (int i = 0; i < 4; ++i)
                Bv[i] = *(const bf16x8*)(&xbL[ch & 1][((chalf * 4 + i) * 64 + lane) * 8]);

            const int gl0 = __builtin_amdgcn_readfirstlane(batch[base]);
            const int gh  = __builtin_amdgcn_readfirstlane(batch[base + 31]);

            if (gl0 == cg && gh == cg) {
                #pragma unroll
                for (int i = 0; i < 4; ++i)
                    pacc[i] = __builtin_amdgcn_mfma_f32_16x16x32_bf16(A.v, Bv[i], pacc[i], 0, 0, 0);
            } else {
                int bt[8];
                #pragma unroll
                for (int j = 0; j < 8; ++j) bt[j] = batch[base + nrow + j];
                while (cg < gh) {
                    union { unsigned short s[8]; bf16x8 v; } Am;
                    #pragma unroll
                    for (int j = 0; j < 8; ++j)
                        Am.s[j] = (bt[j] == cg) ? A.s[j] : (unsigned short)0;
                    #pragma unroll
                    for (int i = 0; i < 4; ++i)
                        pacc[i] = __builtin_amdgcn_mfma_f32_16x16x32_bf16(Am.v, Bv[i], pacc[i], 0, 0, 0);
                    flush(cg);
                    ++cg;
                }
                union { unsigned short s[8]; bf16x8 v; } Am;
                #pragma unroll
                for (int j = 0; j < 8; ++j)
                    Am.s[j] = (bt[j] == cg) ? A.s[j] : (unsigned short)0;
                #pragma unroll
                for (int i = 0; i < 4; ++i)
                    pacc[i] = __builtin_amdgcn_mfma_f32_16x16x32_bf16(Am.v, Bv[i], pacc[i], 0, 0, 0);
            }
        }
    }

    flush(cg);   // pending accumulation
}

// ---------------------------------------------------------------------------
// Kernel 3: out[b] = sum of the NSLOT partial tiles.
// ---------------------------------------------------------------------------
__global__ __launch_bounds__(256) void hp_reduce(const float* __restrict__ part,
                                                 float* __restrict__ out) {
    const int i = (blockIdx.x * 256 + threadIdx.x) * 4;
    if (i < BB * KK * CC) {
        const int b = i >> 12;
        const int j = i & 4095;
        const float* pp = part + (size_t)b * NSLOT * 4096 + j;
        float4 r = make_float4(0.f, 0.f, 0.f, 0.f);
        #pragma unroll 4
        for (int q = 0; q < NSLOT; ++q) {
            const float4 v = *(const float4*)(pp + (size_t)q * 4096);
            r.x += v.x; r.y += v.y; r.z += v.z; r.w += v.w;
        }
        *(float4*)(out + i) = r;
    }
}

// ---------------------------------------------------------------------------
extern "C" void kernel_launch(void* const* d_in, const int* in_sizes, int n_in,
                              void* d_out, int out_size, void* d_ws, size_t ws_size,
                              hipStream_t stream) {
    const float* x     = (const float*)d_in[0];
    const int*   batch = (const int*)d_in[1];
    const float* W1    = (const float*)d_in[2];
    const float* b1    = (const float*)d_in[3];
    const float* W2    = (const float*)d_in[4];
    const float* b2    = (const float*)d_in[5];

    float* out = (float*)d_out;                    // [B,K,C] = 262144 floats
    float* s   = out + (size_t)BB * KK * CC;       // [N,K]   = 3200000 floats

    char* ws = (char*)d_ws;
    int*            bounds = (int*)ws;                          // 512 B
    unsigned short* w1f    = (unsigned short*)(ws + 1024);      // 64 KB
    unsigned short* w2f    = (unsigned short*)(ws + 66560);     // 16 KB
    float*          part   = (float*)(ws + 82944);              // 16.8 MB

    hp_prep<<<256, 256, 0, stream>>>(batch, W1, W2, bounds, w1f, w2f, part);
    const int nblk = (NCHUNK + CH - 1) / CH;       // 782
    hp_fused<<<nblk, 256, 0, stream>>>(x, w1f, w2f, b1, b2, batch, bounds, s, part);
    hp_reduce<<<BB * KK * CC / (256 * 4), 256, 0, stream>>>(part, out);
}

// Round 9
// 161.402 us; speedup vs baseline: 1.0772x; 1.0772x over previous
//
#include <hip/hip_runtime.h>
#include <hip/hip_bf16.h>

#define NN 100000
#define CC 128
#define KK 32
#define BB 64
#define CH 4                // chunks (of 32 nodes) per fused block
#define NCHUNK (NN / 32)    // 3125
#define NSLOT 16            // partial-tile slots per graph (graph <= 14 blocks)

typedef __bf16 bf16x8 __attribute__((ext_vector_type(8)));
typedef float  f32x4  __attribute__((ext_vector_type(4)));

__device__ __forceinline__ unsigned short f2bf(float v) {
    union { __bf16 h; unsigned short s; } u;
    u.h = (__bf16)v;                     // native RNE cvt on gfx950
    return u.s;
}
__device__ __forceinline__ float bf2f(unsigned short h) {
    union { unsigned u; float f; } a; a.u = ((unsigned)h) << 16;
    return a.f;
}
// unpack 8 uints (hi|lo<<16) -> two bf16x8 via v_perm_b32
__device__ __forceinline__ void unpack_hilo(uint4 a, uint4 b,
                                            bf16x8& hi8, bf16x8& lo8) {
    union { unsigned u[4]; bf16x8 v; } H, L;
    H.u[0] = __builtin_amdgcn_perm(a.y, a.x, 0x05040100u);
    H.u[1] = __builtin_amdgcn_perm(a.w, a.z, 0x05040100u);
    H.u[2] = __builtin_amdgcn_perm(b.y, b.x, 0x05040100u);
    H.u[3] = __builtin_amdgcn_perm(b.w, b.z, 0x05040100u);
    L.u[0] = __builtin_amdgcn_perm(a.y, a.x, 0x07060302u);
    L.u[1] = __builtin_amdgcn_perm(a.w, a.z, 0x07060302u);
    L.u[2] = __builtin_amdgcn_perm(b.y, b.x, 0x07060302u);
    L.u[3] = __builtin_amdgcn_perm(b.w, b.z, 0x07060302u);
    hi8 = H.v; lo8 = L.v;
}

// ---------------------------------------------------------------------------
// Kernel 1 (prep): bounds + W1 & W2 -> bf16 hi/lo MFMA B-fragments + zero the
// partial-tile buffer. Grid: 256 blocks x 256 = 65536 threads.
// ---------------------------------------------------------------------------
__global__ __launch_bounds__(256) void hp_prep(const int* __restrict__ batch,
                                               const float* __restrict__ W1,
                                               const float* __restrict__ W2,
                                               int* __restrict__ bounds,
                                               unsigned short* __restrict__ w1f,
                                               unsigned short* __restrict__ w2f,
                                               float* __restrict__ part) {
    if (blockIdx.x == 0 && threadIdx.x <= BB) {
        const int b = threadIdx.x;
        int lo = 0, hi = NN;
        while (lo < hi) {
            const int mid = (lo + hi) >> 1;
            if (batch[mid] < b) lo = mid + 1; else hi = mid;
        }
        bounds[b] = lo;
    }
    const int t = blockIdx.x * 256 + threadIdx.x;
    if (t < 16384) {   // W1 fragments
        const int idx  = t;
        const int j    = idx & 7;
        const int lane = (idx >> 3) & 63;
        const int nt   = (idx >> 9) & 7;
        const int kt   = idx >> 12;
        const int k = kt * 32 + (lane >> 4) * 8 + j;
        const int n = nt * 16 + (lane & 15);
        const float w = W1[k * CC + n];
        const unsigned short h = f2bf(w);
        w1f[idx]         = h;
        w1f[16384 + idx] = f2bf(w - bf2f(h));
    }
    if (t < 4096) {    // W2 fragments
        const int idx  = t;
        const int j    = idx & 7;
        const int lane = (idx >> 3) & 63;
        const int nt   = (idx >> 9) & 1;
        const int kt   = idx >> 10;
        const int k = kt * 32 + (lane >> 4) * 8 + j;
        const int n = nt * 16 + (lane & 15);
        const float w = W2[k * KK + n];
        const unsigned short h = f2bf(w);
        w2f[idx]        = h;
        w2f[4096 + idx] = f2bf(w - bf2f(h));
    }
    // zero the partial-tile buffer [B][NSLOT][K][C] (fused writes sparse slots)
    const float4 z = make_float4(0.f, 0.f, 0.f, 0.f);
    for (int i = t; i < BB * NSLOT * KK * CC / 4; i += 65536)
        *(float4*)(part + (size_t)i * 4) = z;
}

// ---------------------------------------------------------------------------
// Kernel 2 (fused): per block, CH consecutive 32-node chunks.
// 4 barriers per chunk:
//   stage x -> xa + xbL[ch&1] -> B1 -> layer1 MFMA -> B2 -> pack hs16 -> B3 ->
//   { waves 0,1: layer2 both n-halves + in-wave softmax -> lgT } -> B4 ->
//   pool MFMA + s_out store + flush (plain stores to part[g][slot]).
// vs R7: in-wave softmax kills redm/reds + 3 barriers; xbL double-buffer kills
// the top-of-loop barrier; s_out store drains with next chunk's B1 instead of
// a dedicated barrier. No prefetch registers (R8 spill lesson).
// ---------------------------------------------------------------------------
__global__ __launch_bounds__(256, 3) void hp_fused(
    const float* __restrict__ x,
    const unsigned short* __restrict__ w1f,
    const unsigned short* __restrict__ w2f,
    const float* __restrict__ b1,
    const float* __restrict__ b2,
    const int* __restrict__ batch,
    const int* __restrict__ bounds,
    float* __restrict__ s_out,
    float* __restrict__ part)
{
    __shared__ __align__(16) char uni[16896];                   // xa / hs16 overlay
    __shared__ __align__(16) unsigned short xbL[2][8 * 64 * 8]; // 16 KB dbuf B-frags
    __shared__ float lgT[32][36];                               // [node][k] s values

    unsigned short* xa   = (unsigned short*)uni;   // [split][q=mt*4+kt][lane][8]
    unsigned int*   hs16 = (unsigned int*)uni;     // [node][132]: hi | lo<<16

    const int t    = threadIdx.x;
    const int wave = __builtin_amdgcn_readfirstlane(t >> 6);
    const int lane = t & 63;

    const int pmt   = wave & 1;                    // pool: k-half
    const int chalf = wave >> 1;                   // pool: c-half
    const int nrow  = (lane >> 4) * 8;             // pool: first node row of lane

    // hoisted loop-invariant biases
    const float bv_epi0 = b1[(2 * wave + 0) * 16 + (lane & 15)];
    const float bv_epi1 = b1[(2 * wave + 1) * 16 + (lane & 15)];
    const float b2lo = b2[lane & 15];
    const float b2hi = b2[16 + (lane & 15)];

    f32x4 pacc[4];
    #pragma unroll
    for (int i = 0; i < 4; ++i) pacc[i] = (f32x4){0.f, 0.f, 0.f, 0.f};

    int cg = __builtin_amdgcn_readfirstlane(batch[blockIdx.x * (CH * 32)]);

    // flush current accumulator into part[g][slot] (plain stores, no atomics)
    auto flush = [&](int g) {
        const int slot = blockIdx.x - (bounds[g] >> 7);   // 128 nodes per block
        float* op = part + ((size_t)g * NSLOT + slot) * (KK * CC);
        #pragma unroll
        for (int i = 0; i < 4; ++i) {
            const int c = (chalf * 4 + i) * 16 + (lane & 15);
            #pragma unroll
            for (int r = 0; r < 4; ++r) {
                const int k = pmt * 16 + (lane >> 4) * 4 + r;
                op[k * CC + c] = pacc[i][r];
            }
            pacc[i] = (f32x4){0.f, 0.f, 0.f, 0.f};
        }
    };

    #pragma unroll 1
    for (int ch = 0; ch < CH; ++ch) {
        const int chunk = blockIdx.x * CH + ch;
        if (chunk >= NCHUNK) break;
        const int base = chunk * 32;

        // ---- stage x -> bf16 hi/lo A-frags (thread does mt = 0,1; kt = wave) ----
        #pragma unroll
        for (int mt = 0; mt < 2; ++mt) {
            const int q  = mt * 4 + wave;
            const int n  = base + mt * 16 + (lane & 15);
            const int ck = wave * 32 + (lane >> 4) * 8;
            const float4 va = *(const float4*)(x + (size_t)n * CC + ck);
            const float4 vb = *(const float4*)(x + (size_t)n * CC + ck + 4);
            const float v[8] = {va.x, va.y, va.z, va.w, vb.x, vb.y, vb.z, vb.w};
            union { unsigned short s[8]; uint4 u; } H, L;
            #pragma unroll
            for (int j = 0; j < 8; ++j) {
                H.s[j] = f2bf(v[j]);
                L.s[j] = f2bf(v[j] - bf2f(H.s[j]));
            }
            unsigned short* d0 = xa + (q * 64 + lane) * 8;
            *(uint4*)(d0)        = H.u;
            *(uint4*)(d0 + 4096) = L.u;
        }

        // ---- emit pool B-frags into xbL[ch&1] (x re-read is L1-hot) ----
        #pragma unroll
        for (int cc = 0; cc < 2; ++cc) {
            const int ct = wave * 2 + cc;
            const int c  = ct * 16 + (lane & 15);
            const int nb = base + nrow;
            union { unsigned short s[8]; uint4 u; } Hb;
            #pragma unroll
            for (int j = 0; j < 8; ++j)
                Hb.s[j] = f2bf(x[(size_t)(nb + j) * CC + c]);
            *(uint4*)(&xbL[ch & 1][((size_t)ct * 64 + lane) * 8]) = Hb.u;
        }
        __syncthreads();                                         // B1

        // ---- layer-1 MFMA; wave owns n-tiles 2w, 2w+1 ----
        f32x4 acc[2][2];
        #pragma unroll
        for (int mt = 0; mt < 2; ++mt)
            #pragma unroll
            for (int nl = 0; nl < 2; ++nl)
                acc[mt][nl] = (f32x4){0.f, 0.f, 0.f, 0.f};

        #pragma unroll
        for (int kt = 0; kt < 4; ++kt) {
            bf16x8 ah[2], al[2];
            #pragma unroll
            for (int mt = 0; mt < 2; ++mt) {
                ah[mt] = *(const bf16x8*)(xa + ((mt * 4 + kt) * 64 + lane) * 8);
                al[mt] = *(const bf16x8*)(xa + 4096 + ((mt * 4 + kt) * 64 + lane) * 8);
            }
            #pragma unroll
            for (int nl = 0; nl < 2; ++nl) {
                const int nt = 2 * wave + nl;
                const bf16x8 wh = *(const bf16x8*)(w1f + ((kt * 8 + nt) * 64 + lane) * 8);
                const bf16x8 wl = *(const bf16x8*)(w1f + 16384 + ((kt * 8 + nt) * 64 + lane) * 8);
                #pragma unroll
                for (int mt = 0; mt < 2; ++mt) {
                    acc[mt][nl] = __builtin_amdgcn_mfma_f32_16x16x32_bf16(ah[mt], wh, acc[mt][nl], 0, 0, 0);
                    acc[mt][nl] = __builtin_amdgcn_mfma_f32_16x16x32_bf16(al[mt], wh, acc[mt][nl], 0, 0, 0);
                    acc[mt][nl] = __builtin_amdgcn_mfma_f32_16x16x32_bf16(ah[mt], wl, acc[mt][nl], 0, 0, 0);
                }
            }
        }
        __syncthreads();                                         // B2 (xa dead)

        // ---- epilogue: bias+relu, pack hi|lo<<16 -> hs16[node][132] ----
        #pragma unroll
        for (int nl = 0; nl < 2; ++nl) {
            const float bv = nl ? bv_epi1 : bv_epi0;
            const int c = (2 * wave + nl) * 16 + (lane & 15);
            #pragma unroll
            for (int mt = 0; mt < 2; ++mt)
                #pragma unroll
                for (int r = 0; r < 4; ++r) {
                    const int node = mt * 16 + (lane >> 4) * 4 + r;
                    const float h = fmaxf(acc[mt][nl][r] + bv, 0.f);
                    const unsigned short hi = f2bf(h);
                    const unsigned short lo = f2bf(h - bf2f(hi));
                    hs16[node * 132 + c] = (unsigned)hi | ((unsigned)lo << 16);
                }
        }
        __syncthreads();                                         // B3

        // ---- phase 2: waves 0,1 do layer2 (both n-halves) + in-wave softmax ----
        if (wave < 2) {
            const int mt2 = wave;
            f32x4 dacc[2];
            dacc[0] = (f32x4){0.f, 0.f, 0.f, 0.f};
            dacc[1] = (f32x4){0.f, 0.f, 0.f, 0.f};
            #pragma unroll
            for (int kt = 0; kt < 4; ++kt) {
                const unsigned* hp = hs16 + (mt2 * 16 + (lane & 15)) * 132
                                          + kt * 32 + (lane >> 4) * 8;
                const uint4 u0 = *(const uint4*)hp;
                const uint4 u1 = *(const uint4*)(hp + 4);
                bf16x8 ah, al;
                unpack_hilo(u0, u1, ah, al);
                #pragma unroll
                for (int nt2 = 0; nt2 < 2; ++nt2) {
                    const bf16x8 wh = *(const bf16x8*)(w2f + ((kt * 2 + nt2) * 64 + lane) * 8);
                    const bf16x8 wl = *(const bf16x8*)(w2f + 4096 + ((kt * 2 + nt2) * 64 + lane) * 8);
                    dacc[nt2] = __builtin_amdgcn_mfma_f32_16x16x32_bf16(ah, wh, dacc[nt2], 0, 0, 0);
                    dacc[nt2] = __builtin_amdgcn_mfma_f32_16x16x32_bf16(al, wh, dacc[nt2], 0, 0, 0);
                    dacc[nt2] = __builtin_amdgcn_mfma_f32_16x16x32_bf16(ah, wl, dacc[nt2], 0, 0, 0);
                }
            }
            // in-wave softmax: lane holds k = lane&15 (+0/+16); node = (lane>>4)*4+r
            float lg0[4], lg1[4], m[4];
            #pragma unroll
            for (int r = 0; r < 4; ++r) {
                lg0[r] = dacc[0][r] + b2lo;
                lg1[r] = dacc[1][r] + b2hi;
                m[r] = fmaxf(lg0[r], lg1[r]);
            }
            #pragma unroll
            for (int msk = 1; msk < 16; msk <<= 1)
                #pragma unroll
                for (int r = 0; r < 4; ++r)
                    m[r] = fmaxf(m[r], __shfl_xor(m[r], msk));
            float e0[4], e1[4], sm[4];
            #pragma unroll
            for (int r = 0; r < 4; ++r) {
                e0[r] = __expf(lg0[r] - m[r]);
                e1[r] = __expf(lg1[r] - m[r]);
                sm[r] = e0[r] + e1[r];
            }
            #pragma unroll
            for (int msk = 1; msk < 16; msk <<= 1)
                #pragma unroll
                for (int r = 0; r < 4; ++r)
                    sm[r] += __shfl_xor(sm[r], msk);
            #pragma unroll
            for (int r = 0; r < 4; ++r) {
                const float inv = 1.f / sm[r];
                const int node = mt2 * 16 + (lane >> 4) * 4 + r;
                lgT[node][lane & 15]        = e0[r] * inv;
                lgT[node][16 + (lane & 15)] = e1[r] * inv;
            }
        }
        __syncthreads();                                         // B4

        // ---- pool: s^T x accumulate (per-wave quadrant, no barriers) ----
        {
            union { unsigned short s[8]; bf16x8 v; } A;
            const int kA = pmt * 16 + (lane & 15);
            #pragma unroll
            for (int j = 0; j < 8; ++j)
                A.s[j] = f2bf(lgT[nrow + j][kA]);
            bf16x8 Bv[4];
            #pragma unroll
            for (int i = 0; i < 4; ++i)
                Bv[i] = *(const bf16x8*)(&xbL[ch & 1][((size_t)(chalf * 4 + i) * 64 + lane) * 8]);

            const int gl0 = __builtin_amdgcn_readfirstlane(batch[base]);
            const int gh  = __builtin_amdgcn_readfirstlane(batch[base + 31]);

            if (gl0 == cg && gh == cg) {
                #pragma unroll
                for (int i = 0; i < 4; ++i)
                    pacc[i] = __builtin_amdgcn_mfma_f32_16x16x32_bf16(A.v, Bv[i], pacc[i], 0, 0, 0);
            } else {
                int bt[8];
                #pragma unroll
                for (int j = 0; j < 8; ++j) bt[j] = batch[base + nrow + j];
                while (cg < gh) {
                    union { unsigned short s[8]; bf16x8 v; } Am;
                    #pragma unroll
                    for (int j = 0; j < 8; ++j)
                        Am.s[j] = (bt[j] == cg) ? A.s[j] : (unsigned short)0;
                    #pragma unroll
                    for (int i = 0; i < 4; ++i)
                        pacc[i] = __builtin_amdgcn_mfma_f32_16x16x32_bf16(Am.v, Bv[i], pacc[i], 0, 0, 0);
                    flush(cg);
                    ++cg;
                }
                union { unsigned short s[8]; bf16x8 v; } Am;
                #pragma unroll
                for (int j = 0; j < 8; ++j)
                    Am.s[j] = (bt[j] == cg) ? A.s[j] : (unsigned short)0;
                #pragma unroll
                for (int i = 0; i < 4; ++i)
                    pacc[i] = __builtin_amdgcn_mfma_f32_16x16x32_bf16(Am.v, Bv[i], pacc[i], 0, 0, 0);
            }
        }

        // ---- s_out float4 store from lgT (drains with next chunk's B1) ----
        {
            const int node = lane & 31;
            const int koff = ((lane >> 5) << 4) + wave * 4;
            const float4 s4 = *(const float4*)&lgT[node][koff];
            *(float4*)(s_out + (size_t)(base + node) * KK + koff) = s4;
        }
    }

    flush(cg);   // pending accumulation
}

// ---------------------------------------------------------------------------
// Kernel 3: out[b] = sum of the NSLOT partial tiles.
// ---------------------------------------------------------------------------
__global__ __launch_bounds__(256) void hp_reduce(const float* __restrict__ part,
                                                 float* __restrict__ out) {
    const int i = (blockIdx.x * 256 + threadIdx.x) * 4;
    if (i < BB * KK * CC) {
        const int b = i >> 12;
        const int j = i & 4095;
        const float* pp = part + (size_t)b * NSLOT * 4096 + j;
        float4 r = make_float4(0.f, 0.f, 0.f, 0.f);
        #pragma unroll 4
        for (int q = 0; q < NSLOT; ++q) {
            const float4 v = *(const float4*)(pp + (size_t)q * 4096);
            r.x += v.x; r.y += v.y; r.z += v.z; r.w += v.w;
        }
        *(float4*)(out + i) = r;
    }
}

// ---------------------------------------------------------------------------
extern "C" void kernel_launch(void* const* d_in, const int* in_sizes, int n_in,
                              void* d_out, int out_size, void* d_ws, size_t ws_size,
                              hipStream_t stream) {
    const float* x     = (const float*)d_in[0];
    const int*   batch = (const int*)d_in[1];
    const float* W1    = (const float*)d_in[2];
    const float* b1    = (const float*)d_in[3];
    const float* W2    = (const float*)d_in[4];
    const float* b2    = (const float*)d_in[5];

    float* out = (float*)d_out;                    // [B,K,C] = 262144 floats
    float* s   = out + (size_t)BB * KK * CC;       // [N,K]   = 3200000 floats

    char* ws = (char*)d_ws;
    int*            bounds = (int*)ws;                          // 512 B
    unsigned short* w1f    = (unsigned short*)(ws + 1024);      // 64 KB
    unsigned short* w2f    = (unsigned short*)(ws + 66560);     // 16 KB
    float*          part   = (float*)(ws + 82944);              // 16.8 MB

    hp_prep<<<256, 256, 0, stream>>>(batch, W1, W2, bounds, w1f, w2f, part);
    const int nblk = (NCHUNK + CH - 1) / CH;       // 782
    hp_fused<<<nblk, 256, 0, stream>>>(x, w1f, w2f, b1, b2, batch, bounds, s, part);
    hp_reduce<<<BB * KK * CC / (256 * 4), 256, 0, stream>>>(part, out);
}

// Round 10
// 142.732 us; speedup vs baseline: 1.2181x; 1.1308x over previous
//
#include <hip/hip_runtime.h>
#include <hip/hip_bf16.h>

#define NN 100000
#define CC 128
#define KK 32
#define BB 64
#define NCHUNK (NN / 32)    // 3125 (one chunk of 32 nodes per block)
#define NSLOT 64            // partial slots per graph (span <= ~54 chunks)

typedef __bf16 bf16x8 __attribute__((ext_vector_type(8)));
typedef float  f32x4  __attribute__((ext_vector_type(4)));

__device__ __forceinline__ unsigned short f2bf(float v) {
    union { __bf16 h; unsigned short s; } u;
    u.h = (__bf16)v;                     // native RNE cvt on gfx950
    return u.s;
}
__device__ __forceinline__ float bf2f(unsigned short h) {
    union { unsigned u; float f; } a; a.u = ((unsigned)h) << 16;
    return a.f;
}
// unpack 8 uints (hi|lo<<16) -> two bf16x8 via v_perm_b32
__device__ __forceinline__ void unpack_hilo(uint4 a, uint4 b,
                                            bf16x8& hi8, bf16x8& lo8) {
    union { unsigned u[4]; bf16x8 v; } H, L;
    H.u[0] = __builtin_amdgcn_perm(a.y, a.x, 0x05040100u);
    H.u[1] = __builtin_amdgcn_perm(a.w, a.z, 0x05040100u);
    H.u[2] = __builtin_amdgcn_perm(b.y, b.x, 0x05040100u);
    H.u[3] = __builtin_amdgcn_perm(b.w, b.z, 0x05040100u);
    L.u[0] = __builtin_amdgcn_perm(a.y, a.x, 0x07060302u);
    L.u[1] = __builtin_amdgcn_perm(a.w, a.z, 0x07060302u);
    L.u[2] = __builtin_amdgcn_perm(b.y, b.x, 0x07060302u);
    L.u[3] = __builtin_amdgcn_perm(b.w, b.z, 0x07060302u);
    hi8 = H.v; lo8 = L.v;
}

// ---------------------------------------------------------------------------
// Kernel 1 (prep): bounds + W1 & W2 -> bf16 hi/lo MFMA B-fragments.
// No part zeroing needed: every slot in a graph's chunk-span is written by
// exactly one fused block, and hp_reduce sums exactly the span.
// ---------------------------------------------------------------------------
__global__ __launch_bounds__(256) void hp_prep(const int* __restrict__ batch,
                                               const float* __restrict__ W1,
                                               const float* __restrict__ W2,
                                               int* __restrict__ bounds,
                                               unsigned short* __restrict__ w1f,
                                               unsigned short* __restrict__ w2f) {
    if (blockIdx.x == 0 && threadIdx.x <= BB) {
        const int b = threadIdx.x;
        int lo = 0, hi = NN;
        while (lo < hi) {
            const int mid = (lo + hi) >> 1;
            if (batch[mid] < b) lo = mid + 1; else hi = mid;
        }
        bounds[b] = lo;
    }
    const int t = blockIdx.x * 256 + threadIdx.x;
    {   // W1 fragments: 16384 elements, one per thread (64 blocks x 256)
        const int idx  = t;
        const int j    = idx & 7;
        const int lane = (idx >> 3) & 63;
        const int nt   = (idx >> 9) & 7;
        const int kt   = idx >> 12;
        const int k = kt * 32 + (lane >> 4) * 8 + j;
        const int n = nt * 16 + (lane & 15);
        const float w = W1[k * CC + n];
        const unsigned short h = f2bf(w);
        w1f[idx]         = h;
        w1f[16384 + idx] = f2bf(w - bf2f(h));
    }
    if (t < 4096) {    // W2 fragments
        const int idx  = t;
        const int j    = idx & 7;
        const int lane = (idx >> 3) & 63;
        const int nt   = (idx >> 9) & 1;
        const int kt   = idx >> 10;
        const int k = kt * 32 + (lane >> 4) * 8 + j;
        const int n = nt * 16 + (lane & 15);
        const float w = W2[k * KK + n];
        const unsigned short h = f2bf(w);
        w2f[idx]        = h;
        w2f[4096 + idx] = f2bf(w - bf2f(h));
    }
}

// ---------------------------------------------------------------------------
// Kernel 2 (fused): ONE 32-node chunk per block (3125 blocks = 12.2 chains/CU
// through ~4 resident slots -> block-turnover pipelining; CH=4's 782 blocks
// gave zero turnover). Phase structure identical to R7 (the only structure
// that holds 54-57 us). Flush: plain stores to part[g][slot],
// slot = blockIdx.x - (bounds[g]>>5)  (chunk index within graph span).
// ---------------------------------------------------------------------------
__global__ __launch_bounds__(256, 3) void hp_fused(
    const float* __restrict__ x,
    const unsigned short* __restrict__ w1f,
    const unsigned short* __restrict__ w2f,
    const float* __restrict__ b1,
    const float* __restrict__ b2,
    const int* __restrict__ batch,
    const int* __restrict__ bounds,
    float* __restrict__ s_out,
    float* __restrict__ part)
{
    __shared__ __align__(16) char uni[16896];         // xa (16384 B) / hs16 (16896 B)
    __shared__ __align__(16) unsigned short xbL[8 * 64 * 8];   // 8 KB pool B-frags
    __shared__ float lgT[32][36];                     // [node][k] logits, then s
    __shared__ float redm[4][32];
    __shared__ float reds[4][32];

    unsigned short* xa   = (unsigned short*)uni;      // [split][q=mt*4+kt][lane][8]
    unsigned int*   hs16 = (unsigned int*)uni;        // [node][132]: hi | lo<<16

    const int t    = threadIdx.x;
    const int wave = __builtin_amdgcn_readfirstlane(t >> 6);
    const int lane = t & 63;

    const int pmt   = wave & 1;                       // pool: k-half
    const int chalf = wave >> 1;                      // pool: c-half
    const int nrow  = (lane >> 4) * 8;                // pool: first node row of lane

    const int base = blockIdx.x * 32;

    f32x4 pacc[4];
    #pragma unroll
    for (int i = 0; i < 4; ++i) pacc[i] = (f32x4){0.f, 0.f, 0.f, 0.f};

    // flush accumulator into part[g][slot] (plain stores, no atomics)
    auto flush = [&](int g) {
        const int slot = blockIdx.x - (bounds[g] >> 5);   // 32 nodes per block
        float* op = part + ((size_t)g * NSLOT + slot) * (KK * CC);
        #pragma unroll
        for (int i = 0; i < 4; ++i) {
            const int c = (chalf * 4 + i) * 16 + (lane & 15);
            #pragma unroll
            for (int r = 0; r < 4; ++r) {
                const int k = pmt * 16 + (lane >> 4) * 4 + r;
                op[k * CC + c] = pacc[i][r];
            }
            pacc[i] = (f32x4){0.f, 0.f, 0.f, 0.f};
        }
    };

    // ---- stage x -> bf16 hi/lo A-frags (thread does mt = 0,1; kt = wave) ----
    #pragma unroll
    for (int mt = 0; mt < 2; ++mt) {
        const int q  = mt * 4 + wave;
        const int n  = base + mt * 16 + (lane & 15);
        const int ck = wave * 32 + (lane >> 4) * 8;
        const float4 va = *(const float4*)(x + (size_t)n * CC + ck);
        const float4 vb = *(const float4*)(x + (size_t)n * CC + ck + 4);
        const float v[8] = {va.x, va.y, va.z, va.w, vb.x, vb.y, vb.z, vb.w};
        union { unsigned short s[8]; uint4 u; } H, L;
        #pragma unroll
        for (int j = 0; j < 8; ++j) {
            H.s[j] = f2bf(v[j]);
            L.s[j] = f2bf(v[j] - bf2f(H.s[j]));
        }
        unsigned short* d0 = xa + (q * 64 + lane) * 8;
        *(uint4*)(d0)        = H.u;
        *(uint4*)(d0 + 4096) = L.u;
    }

    // ---- emit pool B-frags into LDS (x re-read is L1-hot) ----
    #pragma unroll
    for (int cc = 0; cc < 2; ++cc) {
        const int ct = wave * 2 + cc;
        const int c  = ct * 16 + (lane & 15);
        const int nb = base + nrow;
        union { unsigned short s[8]; uint4 u; } Hb;
        #pragma unroll
        for (int j = 0; j < 8; ++j)
            Hb.s[j] = f2bf(x[(size_t)(nb + j) * CC + c]);
        *(uint4*)(xbL + ((size_t)ct * 64 + lane) * 8) = Hb.u;
    }
    __syncthreads();

    // ---- phase 1: layer-1 MFMA; wave owns n-tiles 2w, 2w+1 ----
    f32x4 acc[2][2];
    #pragma unroll
    for (int mt = 0; mt < 2; ++mt)
        #pragma unroll
        for (int nl = 0; nl < 2; ++nl)
            acc[mt][nl] = (f32x4){0.f, 0.f, 0.f, 0.f};

    #pragma unroll
    for (int kt = 0; kt < 4; ++kt) {
        bf16x8 ah[2], al[2];
        #pragma unroll
        for (int mt = 0; mt < 2; ++mt) {
            ah[mt] = *(const bf16x8*)(xa + ((mt * 4 + kt) * 64 + lane) * 8);
            al[mt] = *(const bf16x8*)(xa + 4096 + ((mt * 4 + kt) * 64 + lane) * 8);
        }
        #pragma unroll
        for (int nl = 0; nl < 2; ++nl) {
            const int nt = 2 * wave + nl;
            const bf16x8 wh = *(const bf16x8*)(w1f + ((kt * 8 + nt) * 64 + lane) * 8);
            const bf16x8 wl = *(const bf16x8*)(w1f + 16384 + ((kt * 8 + nt) * 64 + lane) * 8);
            #pragma unroll
            for (int mt = 0; mt < 2; ++mt) {
                acc[mt][nl] = __builtin_amdgcn_mfma_f32_16x16x32_bf16(ah[mt], wh, acc[mt][nl], 0, 0, 0);
                acc[mt][nl] = __builtin_amdgcn_mfma_f32_16x16x32_bf16(al[mt], wh, acc[mt][nl], 0, 0, 0);
                acc[mt][nl] = __builtin_amdgcn_mfma_f32_16x16x32_bf16(ah[mt], wl, acc[mt][nl], 0, 0, 0);
            }
        }
    }
    __syncthreads();                               // xa dead; hs16 overlays

    // ---- epilogue: bias+relu, pack hi|lo<<16 -> hs16[node][132] ----
    #pragma unroll
    for (int nl = 0; nl < 2; ++nl) {
        const int c = (2 * wave + nl) * 16 + (lane & 15);
        const float bv = b1[c];
        #pragma unroll
        for (int mt = 0; mt < 2; ++mt)
            #pragma unroll
            for (int r = 0; r < 4; ++r) {
                const int node = mt * 16 + (lane >> 4) * 4 + r;
                const float h = fmaxf(acc[mt][nl][r] + bv, 0.f);
                const unsigned short hi = f2bf(h);
                const unsigned short lo = f2bf(h - bf2f(hi));
                hs16[node * 132 + c] = (unsigned)hi | ((unsigned)lo << 16);
            }
    }
    __syncthreads();

    // ---- phase 2: logits via MFMA; wave = (mt2 = w&1, nt2 = w>>1) ----
    {
        const int mt2 = wave & 1, nt2 = wave >> 1;
        f32x4 dacc = (f32x4){0.f, 0.f, 0.f, 0.f};
        #pragma unroll
        for (int kt = 0; kt < 4; ++kt) {
            const unsigned* hp = hs16 + (mt2 * 16 + (lane & 15)) * 132
                                      + kt * 32 + (lane >> 4) * 8;
            const uint4 u0 = *(const uint4*)hp;
            const uint4 u1 = *(const uint4*)(hp + 4);
            bf16x8 ah, al;
            unpack_hilo(u0, u1, ah, al);
            const bf16x8 wh = *(const bf16x8*)(w2f + ((kt * 2 + nt2) * 64 + lane) * 8);
            const bf16x8 wl = *(const bf16x8*)(w2f + 4096 + ((kt * 2 + nt2) * 64 + lane) * 8);
            dacc = __builtin_amdgcn_mfma_f32_16x16x32_bf16(ah, wh, dacc, 0, 0, 0);
            dacc = __builtin_amdgcn_mfma_f32_16x16x32_bf16(al, wh, dacc, 0, 0, 0);
            dacc = __builtin_amdgcn_mfma_f32_16x16x32_bf16(ah, wl, dacc, 0, 0, 0);
        }
        const int kcol = nt2 * 16 + (lane & 15);
        #pragma unroll
        for (int r = 0; r < 4; ++r) {
            const int node = mt2 * 16 + (lane >> 4) * 4 + r;
            lgT[node][kcol] = dacc[r];
        }
    }
    __syncthreads();

    // ---- phase 3: softmax (2-round LDS combine) ----
    {
        const int node = lane & 31;
        const int koff = ((lane >> 5) << 4) + wave * 4;
        const float4 bv2 = *(const float4*)(b2 + koff);
        const float4 lv  = *(const float4*)&lgT[node][koff];
        float lg[4] = {lv.x + bv2.x, lv.y + bv2.y, lv.z + bv2.z, lv.w + bv2.w};

        float m = fmaxf(fmaxf(lg[0], lg[1]), fmaxf(lg[2], lg[3]));
        m = fmaxf(m, __shfl_xor(m, 32));
        if (lane < 32) redm[wave][lane] = m;
        __syncthreads();
        const float M = fmaxf(fmaxf(redm[0][node], redm[1][node]),
                              fmaxf(redm[2][node], redm[3][node]));
        const float e0 = __expf(lg[0] - M);
        const float e1 = __expf(lg[1] - M);
        const float e2 = __expf(lg[2] - M);
        const float e3 = __expf(lg[3] - M);
        float sp = (e0 + e1) + (e2 + e3);
        sp += __shfl_xor(sp, 32);
        if (lane < 32) reds[wave][lane] = sp;
        __syncthreads();
        const float S = (reds[0][node] + reds[1][node]) + (reds[2][node] + reds[3][node]);
        const float inv = 1.f / S;
        const float4 s4 = make_float4(e0 * inv, e1 * inv, e2 * inv, e3 * inv);
        *(float4*)(s_out + (size_t)(base + node) * KK + koff) = s4;
        *(float4*)&lgT[node][koff] = s4;           // normalized s for pool
    }
    __syncthreads();

    // ---- pool phase: s^T x accumulate + flush (per-wave quadrant) ----
    {
        union { unsigned short s[8]; bf16x8 v; } A;
        const int kA = pmt * 16 + (lane & 15);
        #pragma unroll
        for (int j = 0; j < 8; ++j)
            A.s[j] = f2bf(lgT[nrow + j][kA]);
        bf16x8 Bv[4];
        #pragma unroll
        for (int i = 0; i < 4; ++i)
            Bv[i] = *(const bf16x8*)(xbL + ((size_t)(chalf * 4 + i) * 64 + lane) * 8);

        const int gl0 = __builtin_amdgcn_readfirstlane(batch[base]);
        const int gh  = __builtin_amdgcn_readfirstlane(batch[base + 31]);
        int cg = gl0;

        if (gl0 == gh) {
            #pragma unroll
            for (int i = 0; i < 4; ++i)
                pacc[i] = __builtin_amdgcn_mfma_f32_16x16x32_bf16(A.v, Bv[i], pacc[i], 0, 0, 0);
        } else {
            int bt[8];
            #pragma unroll
            for (int j = 0; j < 8; ++j) bt[j] = batch[base + nrow + j];
            while (cg < gh) {
                union { unsigned short s[8]; bf16x8 v; } Am;
                #pragma unroll
                for (int j = 0; j < 8; ++j)
                    Am.s[j] = (bt[j] == cg) ? A.s[j] : (unsigned short)0;
                #pragma unroll
                for (int i = 0; i < 4; ++i)
                    pacc[i] = __builtin_amdgcn_mfma_f32_16x16x32_bf16(Am.v, Bv[i], pacc[i], 0, 0, 0);
                flush(cg);
                ++cg;
            }
            union { unsigned short s[8]; bf16x8 v; } Am;
            #pragma unroll
            for (int j = 0; j < 8; ++j)
                Am.s[j] = (bt[j] == cg) ? A.s[j] : (unsigned short)0;
            #pragma unroll
            for (int i = 0; i < 4; ++i)
                pacc[i] = __builtin_amdgcn_mfma_f32_16x16x32_bf16(Am.v, Bv[i], pacc[i], 0, 0, 0);
        }

        flush(cg);   // final (graph gh's slot for this chunk)
    }
}

// ---------------------------------------------------------------------------
// Kernel 3: out[g] = sum of part[g][0 .. span-1] (exactly the written slots).
// Grid: 256 blocks = 64 graphs x 4 quarters of the [K,C] tile.
// ---------------------------------------------------------------------------
__global__ __launch_bounds__(256) void hp_reduce(const float* __restrict__ part,
                                                 const int* __restrict__ bounds,
                                                 float* __restrict__ out) {
    const int g = blockIdx.x >> 2;
    const int q = blockIdx.x & 3;
    const int j = q * 1024 + threadIdx.x * 4;
    const int c0 = bounds[g] >> 5;
    const int c1 = (bounds[g + 1] - 1) >> 5;
    const int span = (bounds[g + 1] > bounds[g]) ? (c1 - c0 + 1) : 0;
    const float* pp = part + (size_t)g * NSLOT * 4096 + j;
    float4 r = make_float4(0.f, 0.f, 0.f, 0.f);
    for (int s = 0; s < span; ++s) {
        const float4 v = *(const float4*)(pp + (size_t)s * 4096);
        r.x += v.x; r.y += v.y; r.z += v.z; r.w += v.w;
    }
    *(float4*)(out + (size_t)g * 4096 + j) = r;
}

// ---------------------------------------------------------------------------
extern "C" void kernel_launch(void* const* d_in, const int* in_sizes, int n_in,
                              void* d_out, int out_size, void* d_ws, size_t ws_size,
                              hipStream_t stream) {
    const float* x     = (const float*)d_in[0];
    const int*   batch = (const int*)d_in[1];
    const float* W1    = (const float*)d_in[2];
    const float* b1    = (const float*)d_in[3];
    const float* W2    = (const float*)d_in[4];
    const float* b2    = (const float*)d_in[5];

    float* out = (float*)d_out;                    // [B,K,C] = 262144 floats
    float* s   = out + (size_t)BB * KK * CC;       // [N,K]   = 3200000 floats

    char* ws = (char*)d_ws;
    int*            bounds = (int*)ws;                          // 512 B
    unsigned short* w1f    = (unsigned short*)(ws + 1024);      // 64 KB
    unsigned short* w2f    = (unsigned short*)(ws + 66560);     // 16 KB
    float*          part   = (float*)(ws + 82944);              // 67.1 MB

    hp_prep<<<64, 256, 0, stream>>>(batch, W1, W2, bounds, w1f, w2f);
    hp_fused<<<NCHUNK, 256, 0, stream>>>(x, w1f, w2f, b1, b2, batch, bounds, s, part);
    hp_reduce<<<BB * 4, 256, 0, stream>>>(part, bounds, out);
}

// Round 11
// 136.921 us; speedup vs baseline: 1.2698x; 1.0424x over previous
//
#include <hip/hip_runtime.h>
#include <hip/hip_bf16.h>

#define NN 100000
#define CC 128
#define KK 32
#define BB 64
#define NCHUNK (NN / 32)    // 3125 (one chunk of 32 nodes per block)
#define NSLOT 56            // partial slots per graph (actual span ~50-53)
#define NSG 7               // slot groups of 8 (ceil(56/8))

typedef __bf16 bf16x8 __attribute__((ext_vector_type(8)));
typedef float  f32x4  __attribute__((ext_vector_type(4)));

__device__ __forceinline__ unsigned short f2bf(float v) {
    union { __bf16 h; unsigned short s; } u;
    u.h = (__bf16)v;                     // native RNE cvt on gfx950
    return u.s;
}
__device__ __forceinline__ float bf2f(unsigned short h) {
    union { unsigned u; float f; } a; a.u = ((unsigned)h) << 16;
    return a.f;
}
// unpack 8 uints (hi|lo<<16) -> two bf16x8 via v_perm_b32
__device__ __forceinline__ void unpack_hilo(uint4 a, uint4 b,
                                            bf16x8& hi8, bf16x8& lo8) {
    union { unsigned u[4]; bf16x8 v; } H, L;
    H.u[0] = __builtin_amdgcn_perm(a.y, a.x, 0x05040100u);
    H.u[1] = __builtin_amdgcn_perm(a.w, a.z, 0x05040100u);
    H.u[2] = __builtin_amdgcn_perm(b.y, b.x, 0x05040100u);
    H.u[3] = __builtin_amdgcn_perm(b.w, b.z, 0x05040100u);
    L.u[0] = __builtin_amdgcn_perm(a.y, a.x, 0x07060302u);
    L.u[1] = __builtin_amdgcn_perm(a.w, a.z, 0x07060302u);
    L.u[2] = __builtin_amdgcn_perm(b.y, b.x, 0x07060302u);
    L.u[3] = __builtin_amdgcn_perm(b.w, b.z, 0x07060302u);
    hi8 = H.v; lo8 = L.v;
}

// ---------------------------------------------------------------------------
// Kernel 1 (prep): bounds + W1 & W2 -> bf16 hi/lo MFMA B-fragments.
// ---------------------------------------------------------------------------
__global__ __launch_bounds__(256) void hp_prep(const int* __restrict__ batch,
                                               const float* __restrict__ W1,
                                               const float* __restrict__ W2,
                                               int* __restrict__ bounds,
                                               unsigned short* __restrict__ w1f,
                                               unsigned short* __restrict__ w2f) {
    if (blockIdx.x == 0 && threadIdx.x <= BB) {
        const int b = threadIdx.x;
        int lo = 0, hi = NN;
        while (lo < hi) {
            const int mid = (lo + hi) >> 1;
            if (batch[mid] < b) lo = mid + 1; else hi = mid;
        }
        bounds[b] = lo;
    }
    const int t = blockIdx.x * 256 + threadIdx.x;
    {   // W1 fragments: 16384 elements, one per thread (64 blocks x 256)
        const int idx  = t;
        const int j    = idx & 7;
        const int lane = (idx >> 3) & 63;
        const int nt   = (idx >> 9) & 7;
        const int kt   = idx >> 12;
        const int k = kt * 32 + (lane >> 4) * 8 + j;
        const int n = nt * 16 + (lane & 15);
        const float w = W1[k * CC + n];
        const unsigned short h = f2bf(w);
        w1f[idx]         = h;
        w1f[16384 + idx] = f2bf(w - bf2f(h));
    }
    if (t < 4096) {    // W2 fragments
        const int idx  = t;
        const int j    = idx & 7;
        const int lane = (idx >> 3) & 63;
        const int nt   = (idx >> 9) & 1;
        const int kt   = idx >> 10;
        const int k = kt * 32 + (lane >> 4) * 8 + j;
        const int n = nt * 16 + (lane & 15);
        const float w = W2[k * KK + n];
        const unsigned short h = f2bf(w);
        w2f[idx]        = h;
        w2f[4096 + idx] = f2bf(w - bf2f(h));
    }
}

// ---------------------------------------------------------------------------
// Kernel 2 (fused): ONE 32-node chunk per block. Identical to R10 except
// launch_bounds(256,5): VGPR cap ~48 >= 44 used (no spill; 256/k law), LDS
// 30.7KB x5 = 153.6KB fits -> up to 5 resident blocks/CU for deeper overlap.
// ---------------------------------------------------------------------------
__global__ __launch_bounds__(256, 5) void hp_fused(
    const float* __restrict__ x,
    const unsigned short* __restrict__ w1f,
    const unsigned short* __restrict__ w2f,
    const float* __restrict__ b1,
    const float* __restrict__ b2,
    const int* __restrict__ batch,
    const int* __restrict__ bounds,
    float* __restrict__ s_out,
    float* __restrict__ part)
{
    __shared__ __align__(16) char uni[16896];         // xa (16384 B) / hs16 (16896 B)
    __shared__ __align__(16) unsigned short xbL[8 * 64 * 8];   // 8 KB pool B-frags
    __shared__ float lgT[32][36];                     // [node][k] logits, then s
    __shared__ float redm[4][32];
    __shared__ float reds[4][32];

    unsigned short* xa   = (unsigned short*)uni;      // [split][q=mt*4+kt][lane][8]
    unsigned int*   hs16 = (unsigned int*)uni;        // [node][132]: hi | lo<<16

    const int t    = threadIdx.x;
    const int wave = __builtin_amdgcn_readfirstlane(t >> 6);
    const int lane = t & 63;

    const int pmt   = wave & 1;                       // pool: k-half
    const int chalf = wave >> 1;                      // pool: c-half
    const int nrow  = (lane >> 4) * 8;                // pool: first node row of lane

    const int base = blockIdx.x * 32;

    f32x4 pacc[4];
    #pragma unroll
    for (int i = 0; i < 4; ++i) pacc[i] = (f32x4){0.f, 0.f, 0.f, 0.f};

    // flush accumulator into part[g][slot] (plain stores, no atomics)
    auto flush = [&](int g) {
        const int slot = blockIdx.x - (bounds[g] >> 5);   // 32 nodes per block
        float* op = part + ((size_t)g * NSLOT + slot) * (KK * CC);
        #pragma unroll
        for (int i = 0; i < 4; ++i) {
            const int c = (chalf * 4 + i) * 16 + (lane & 15);
            #pragma unroll
            for (int r = 0; r < 4; ++r) {
                const int k = pmt * 16 + (lane >> 4) * 4 + r;
                op[k * CC + c] = pacc[i][r];
            }
            pacc[i] = (f32x4){0.f, 0.f, 0.f, 0.f};
        }
    };

    // ---- stage x -> bf16 hi/lo A-frags (thread does mt = 0,1; kt = wave) ----
    #pragma unroll
    for (int mt = 0; mt < 2; ++mt) {
        const int q  = mt * 4 + wave;
        const int n  = base + mt * 16 + (lane & 15);
        const int ck = wave * 32 + (lane >> 4) * 8;
        const float4 va = *(const float4*)(x + (size_t)n * CC + ck);
        const float4 vb = *(const float4*)(x + (size_t)n * CC + ck + 4);
        const float v[8] = {va.x, va.y, va.z, va.w, vb.x, vb.y, vb.z, vb.w};
        union { unsigned short s[8]; uint4 u; } H, L;
        #pragma unroll
        for (int j = 0; j < 8; ++j) {
            H.s[j] = f2bf(v[j]);
            L.s[j] = f2bf(v[j] - bf2f(H.s[j]));
        }
        unsigned short* d0 = xa + (q * 64 + lane) * 8;
        *(uint4*)(d0)        = H.u;
        *(uint4*)(d0 + 4096) = L.u;
    }

    // ---- emit pool B-frags into LDS (x re-read is L1-hot) ----
    #pragma unroll
    for (int cc = 0; cc < 2; ++cc) {
        const int ct = wave * 2 + cc;
        const int c  = ct * 16 + (lane & 15);
        const int nb = base + nrow;
        union { unsigned short s[8]; uint4 u; } Hb;
        #pragma unroll
        for (int j = 0; j < 8; ++j)
            Hb.s[j] = f2bf(x[(size_t)(nb + j) * CC + c]);
        *(uint4*)(xbL + ((size_t)ct * 64 + lane) * 8) = Hb.u;
    }
    __syncthreads();

    // ---- phase 1: layer-1 MFMA; wave owns n-tiles 2w, 2w+1 ----
    f32x4 acc[2][2];
    #pragma unroll
    for (int mt = 0; mt < 2; ++mt)
        #pragma unroll
        for (int nl = 0; nl < 2; ++nl)
            acc[mt][nl] = (f32x4){0.f, 0.f, 0.f, 0.f};

    #pragma unroll
    for (int kt = 0; kt < 4; ++kt) {
        bf16x8 ah[2], al[2];
        #pragma unroll
        for (int mt = 0; mt < 2; ++mt) {
            ah[mt] = *(const bf16x8*)(xa + ((mt * 4 + kt) * 64 + lane) * 8);
            al[mt] = *(const bf16x8*)(xa + 4096 + ((mt * 4 + kt) * 64 + lane) * 8);
        }
        #pragma unroll
        for (int nl = 0; nl < 2; ++nl) {
            const int nt = 2 * wave + nl;
            const bf16x8 wh = *(const bf16x8*)(w1f + ((kt * 8 + nt) * 64 + lane) * 8);
            const bf16x8 wl = *(const bf16x8*)(w1f + 16384 + ((kt * 8 + nt) * 64 + lane) * 8);
            #pragma unroll
            for (int mt = 0; mt < 2; ++mt) {
                acc[mt][nl] = __builtin_amdgcn_mfma_f32_16x16x32_bf16(ah[mt], wh, acc[mt][nl], 0, 0, 0);
                acc[mt][nl] = __builtin_amdgcn_mfma_f32_16x16x32_bf16(al[mt], wh, acc[mt][nl], 0, 0, 0);
                acc[mt][nl] = __builtin_amdgcn_mfma_f32_16x16x32_bf16(ah[mt], wl, acc[mt][nl], 0, 0, 0);
            }
        }
    }
    __syncthreads();                               // xa dead; hs16 overlays

    // ---- epilogue: bias+relu, pack hi|lo<<16 -> hs16[node][132] ----
    #pragma unroll
    for (int nl = 0; nl < 2; ++nl) {
        const int c = (2 * wave + nl) * 16 + (lane & 15);
        const float bv = b1[c];
        #pragma unroll
        for (int mt = 0; mt < 2; ++mt)
            #pragma unroll
            for (int r = 0; r < 4; ++r) {
                const int node = mt * 16 + (lane >> 4) * 4 + r;
                const float h = fmaxf(acc[mt][nl][r] + bv, 0.f);
                const unsigned short hi = f2bf(h);
                const unsigned short lo = f2bf(h - bf2f(hi));
                hs16[node * 132 + c] = (unsigned)hi | ((unsigned)lo << 16);
            }
    }
    __syncthreads();

    // ---- phase 2: logits via MFMA; wave = (mt2 = w&1, nt2 = w>>1) ----
    {
        const int mt2 = wave & 1, nt2 = wave >> 1;
        f32x4 dacc = (f32x4){0.f, 0.f, 0.f, 0.f};
        #pragma unroll
        for (int kt = 0; kt < 4; ++kt) {
            const unsigned* hp = hs16 + (mt2 * 16 + (lane & 15)) * 132
                                      + kt * 32 + (lane >> 4) * 8;
            const uint4 u0 = *(const uint4*)hp;
            const uint4 u1 = *(const uint4*)(hp + 4);
            bf16x8 ah, al;
            unpack_hilo(u0, u1, ah, al);
            const bf16x8 wh = *(const bf16x8*)(w2f + ((kt * 2 + nt2) * 64 + lane) * 8);
            const bf16x8 wl = *(const bf16x8*)(w2f + 4096 + ((kt * 2 + nt2) * 64 + lane) * 8);
            dacc = __builtin_amdgcn_mfma_f32_16x16x32_bf16(ah, wh, dacc, 0, 0, 0);
            dacc = __builtin_amdgcn_mfma_f32_16x16x32_bf16(al, wh, dacc, 0, 0, 0);
            dacc = __builtin_amdgcn_mfma_f32_16x16x32_bf16(ah, wl, dacc, 0, 0, 0);
        }
        const int kcol = nt2 * 16 + (lane & 15);
        #pragma unroll
        for (int r = 0; r < 4; ++r) {
            const int node = mt2 * 16 + (lane >> 4) * 4 + r;
            lgT[node][kcol] = dacc[r];
        }
    }
    __syncthreads();

    // ---- phase 3: softmax (2-round LDS combine) ----
    {
        const int node = lane & 31;
        const int koff = ((lane >> 5) << 4) + wave * 4;
        const float4 bv2 = *(const float4*)(b2 + koff);
        const float4 lv  = *(const float4*)&lgT[node][koff];
        float lg[4] = {lv.x + bv2.x, lv.y + bv2.y, lv.z + bv2.z, lv.w + bv2.w};

        float m = fmaxf(fmaxf(lg[0], lg[1]), fmaxf(lg[2], lg[3]));
        m = fmaxf(m, __shfl_xor(m, 32));
        if (lane < 32) redm[wave][lane] = m;
        __syncthreads();
        const float M = fmaxf(fmaxf(redm[0][node], redm[1][node]),
                              fmaxf(redm[2][node], redm[3][node]));
        const float e0 = __expf(lg[0] - M);
        const float e1 = __expf(lg[1] - M);
        const float e2 = __expf(lg[2] - M);
        const float e3 = __expf(lg[3] - M);
        float sp = (e0 + e1) + (e2 + e3);
        sp += __shfl_xor(sp, 32);
        if (lane < 32) reds[wave][lane] = sp;
        __syncthreads();
        const float S = (reds[0][node] + reds[1][node]) + (reds[2][node] + reds[3][node]);
        const float inv = 1.f / S;
        const float4 s4 = make_float4(e0 * inv, e1 * inv, e2 * inv, e3 * inv);
        *(float4*)(s_out + (size_t)(base + node) * KK + koff) = s4;
        *(float4*)&lgT[node][koff] = s4;           // normalized s for pool
    }
    __syncthreads();

    // ---- pool phase: s^T x accumulate + flush (per-wave quadrant) ----
    {
        union { unsigned short s[8]; bf16x8 v; } A;
        const int kA = pmt * 16 + (lane & 15);
        #pragma unroll
        for (int j = 0; j < 8; ++j)
            A.s[j] = f2bf(lgT[nrow + j][kA]);
        bf16x8 Bv[4];
        #pragma unroll
        for (int i = 0; i < 4; ++i)
            Bv[i] = *(const bf16x8*)(xbL + ((size_t)(chalf * 4 + i) * 64 + lane) * 8);

        const int gl0 = __builtin_amdgcn_readfirstlane(batch[base]);
        const int gh  = __builtin_amdgcn_readfirstlane(batch[base + 31]);
        int cg = gl0;

        if (gl0 == gh) {
            #pragma unroll
            for (int i = 0; i < 4; ++i)
                pacc[i] = __builtin_amdgcn_mfma_f32_16x16x32_bf16(A.v, Bv[i], pacc[i], 0, 0, 0);
        } else {
            int bt[8];
            #pragma unroll
            for (int j = 0; j < 8; ++j) bt[j] = batch[base + nrow + j];
            while (cg < gh) {
                union { unsigned short s[8]; bf16x8 v; } Am;
                #pragma unroll
                for (int j = 0; j < 8; ++j)
                    Am.s[j] = (bt[j] == cg) ? A.s[j] : (unsigned short)0;
                #pragma unroll
                for (int i = 0; i < 4; ++i)
                    pacc[i] = __builtin_amdgcn_mfma_f32_16x16x32_bf16(Am.v, Bv[i], pacc[i], 0, 0, 0);
                flush(cg);
                ++cg;
            }
            union { unsigned short s[8]; bf16x8 v; } Am;
            #pragma unroll
            for (int j = 0; j < 8; ++j)
                Am.s[j] = (bt[j] == cg) ? A.s[j] : (unsigned short)0;
            #pragma unroll
            for (int i = 0; i < 4; ++i)
                pacc[i] = __builtin_amdgcn_mfma_f32_16x16x32_bf16(Am.v, Bv[i], pacc[i], 0, 0, 0);
        }

        flush(cg);   // final (graph gh's slot for this chunk)
    }
}

// ---------------------------------------------------------------------------
// Kernel 3a: stage-1 reduce. Grid = 64 g x 4 quarters x NSG slot-groups.
// Each block sums <= 8 slots of part[g][*] for its quarter -> part2.
// ---------------------------------------------------------------------------
__global__ __launch_bounds__(256) void hp_reduce1(const float* __restrict__ part,
                                                  const int* __restrict__ bounds,
                                                  float* __restrict__ part2) {
    const int sg = blockIdx.x % NSG;
    const int gq = blockIdx.x / NSG;
    const int q  = gq & 3;
    const int g  = gq >> 2;
    const int j  = q * 1024 + threadIdx.x * 4;
    const int c0 = bounds[g] >> 5;
    const int c1 = (bounds[g + 1] - 1) >> 5;
    const int span = (bounds[g + 1] > bounds[g]) ? (c1 - c0 + 1) : 0;
    const int s0 = sg * 8;
    const int s1 = min(s0 + 8, span);
    const float* pp = part + (size_t)g * NSLOT * 4096 + j;
    float4 r = make_float4(0.f, 0.f, 0.f, 0.f);
    for (int s = s0; s < s1; ++s) {
        const float4 v = *(const float4*)(pp + (size_t)s * 4096);
        r.x += v.x; r.y += v.y; r.z += v.z; r.w += v.w;
    }
    *(float4*)(part2 + (size_t)(g * NSG + sg) * 4096 + j) = r;
}

// ---------------------------------------------------------------------------
// Kernel 3b: stage-2 reduce. Grid = 64 g x 4 quarters; sum NSG group entries.
// ---------------------------------------------------------------------------
__global__ __launch_bounds__(256) void hp_reduce2(const float* __restrict__ part2,
                                                  float* __restrict__ out) {
    const int g = blockIdx.x >> 2;
    const int q = blockIdx.x & 3;
    const int j = q * 1024 + threadIdx.x * 4;
    const float* pp = part2 + (size_t)g * NSG * 4096 + j;
    float4 r = make_float4(0.f, 0.f, 0.f, 0.f);
    #pragma unroll
    for (int s = 0; s < NSG; ++s) {
        const float4 v = *(const float4*)(pp + (size_t)s * 4096);
        r.x += v.x; r.y += v.y; r.z += v.z; r.w += v.w;
    }
    *(float4*)(out + (size_t)g * 4096 + j) = r;
}

// ---------------------------------------------------------------------------
extern "C" void kernel_launch(void* const* d_in, const int* in_sizes, int n_in,
                              void* d_out, int out_size, void* d_ws, size_t ws_size,
                              hipStream_t stream) {
    const float* x     = (const float*)d_in[0];
    const int*   batch = (const int*)d_in[1];
    const float* W1    = (const float*)d_in[2];
    const float* b1    = (const float*)d_in[3];
    const float* W2    = (const float*)d_in[4];
    const float* b2    = (const float*)d_in[5];

    float* out = (float*)d_out;                    // [B,K,C] = 262144 floats
    float* s   = out + (size_t)BB * KK * CC;       // [N,K]   = 3200000 floats

    char* ws = (char*)d_ws;
    int*            bounds = (int*)ws;                          // 512 B
    unsigned short* w1f    = (unsigned short*)(ws + 1024);      // 64 KB
    unsigned short* w2f    = (unsigned short*)(ws + 66560);     // 16 KB
    float*          part   = (float*)(ws + 82944);              // 58.7 MB
    float*          part2  = (float*)(ws + 82944 + (size_t)BB * NSLOT * KK * CC * 4); // 7.2 MB

    hp_prep<<<64, 256, 0, stream>>>(batch, W1, W2, bounds, w1f, w2f);
    hp_fused<<<NCHUNK, 256, 0, stream>>>(x, w1f, w2f, b1, b2, batch, bounds, s, part);
    hp_reduce1<<<BB * 4 * NSG, 256, 0, stream>>>(part, bounds, part2);
    hp_reduce2<<<BB * 4, 256, 0, stream>>>(part2, out);
}